// Round 2
// baseline (582.177 us; speedup 1.0000x reference)
//
#include <hip/hip_runtime.h>
#include <hip/hip_fp16.h>

// Problem constants (from reference): OUT=4096, IN=4096, G=16, TOK=8192
#define M_TOK 8192
#define N_OUT 4096
#define K_IN  4096
#define GRP   16

typedef __bf16 bf16x8 __attribute__((ext_vector_type(8)));
typedef float  f32x4  __attribute__((ext_vector_type(4)));
typedef unsigned short ushort8 __attribute__((ext_vector_type(8)));

__device__ __forceinline__ float bfbits(unsigned short h) {
    unsigned int u = ((unsigned int)h) << 16;
    return __builtin_bit_cast(float, u);
}

// async global->LDS, 16B per lane. LDS dest = wave-uniform base + lane*16 (linear).
#define GLDS16(gp, sp) __builtin_amdgcn_global_load_lds(                      \
        (const __attribute__((address_space(1))) void*)(gp),                  \
        (__attribute__((address_space(3))) void*)(sp), 16, 0, 0)

// ---------------------------------------------------------------------------
// Wave-parallel dtype detection (per block; replaces the serial 1-thread
// kernel, whose early-break loops serialized ~160 dependent global loads).
// Predicate logic identical to the previously-verified serial version:
//   s_modes[0]: x storage    1=bf16, 0=f32   (even halfwords 0..126)
//   s_modes[1]: norm storage 0=fp16, 1=bf16, 2=f32  (halfwords 0..31)
//   s_modes[2]: bias storage 1=bf16, 0=f32   (even halfwords 0..126)
// All reads stay within 254 B of each tensor (< any input size). L2-hot after
// the first block touches them.
// ---------------------------------------------------------------------------
__device__ __forceinline__ void detect_block(const void* __restrict__ xv,
                                             const void* __restrict__ nrmv,
                                             const void* __restrict__ biasv,
                                             int* s_modes) {
    const int tid = threadIdx.x;
    if (tid < 64) {
        const unsigned short* px = (const unsigned short*)xv;
        unsigned short hx = px[tid * 2];
        int ex = (hx >> 7) & 0xFF;
        bool xok = ((ex >= 64 && ex <= 134) || (hx & 0x7FFF) == 0);
        unsigned long long xb = __ballot(xok);

        const unsigned short* pn = (const unsigned short*)nrmv;
        unsigned short hn = pn[tid & 31];   // lanes 32..63 duplicate 0..31 (same data)
        float v16 = __half2float(__builtin_bit_cast(__half, hn));
        float vbf = bfbits(hn);
        unsigned long long b16 = __ballot(v16 > 0.0085f && v16 < 1.02f);  // NaN->false
        unsigned long long bbf = __ballot(vbf > 0.0085f && vbf < 1.02f);

        const unsigned short* pb = (const unsigned short*)biasv;
        unsigned short hb = pb[tid * 2];
        int eb = (hb >> 7) & 0xFF;
        bool bok = ((eb >= 64 && eb <= 134) || (hb & 0x7FFF) == 0);
        unsigned long long bb = __ballot(bok);

        if (tid == 0) {
            s_modes[0] = (xb == ~0ULL) ? 1 : 0;
            s_modes[1] = (b16 == ~0ULL) ? 0 : ((bbf == ~0ULL) ? 1 : 2);
            s_modes[2] = (bb == ~0ULL) ? 1 : 0;
        }
    }
    __syncthreads();
}

// ---------------------------------------------------------------------------
// Fused prep kernel: blocks [0,4096) dequant W -> bf16 ws; blocks [4096,6144)
// convert x f32->bf16 ws (early-exit if x already bf16). One launch replaces
// three (detect + prep_w + prep_x).
// ---------------------------------------------------------------------------
__global__ __launch_bounds__(256) void prep_all(const void* __restrict__ xv,
                                                const int* __restrict__ q4,
                                                const void* __restrict__ nrmv,
                                                const void* __restrict__ biasv,
                                                __bf16* __restrict__ W,
                                                __bf16* __restrict__ X) {
    __shared__ int s_modes[3];
    detect_block(xv, nrmv, biasv, s_modes);
    const int tid = threadIdx.x;

    if (blockIdx.x < 4096) {
        // ---- W dequant: one thread per 16-wide group ----
        const int nmode = s_modes[1];
        const int t = blockIdx.x * 256 + tid;              // 0 .. N*K/G-1
        const int4* qp = (const int4*)q4 + (size_t)t * 2;  // 8 int32 = 16 nibble pairs
        int4 a4 = qp[0], c4 = qp[1];
        float nm;
        if (nmode == 0)      nm = __half2float(((const __half*)nrmv)[t]);
        else if (nmode == 1) nm = bfbits(((const unsigned short*)nrmv)[t]);
        else                 nm = ((const float*)nrmv)[t];
        float s = nm * (2.0f / 15.0f);   // w = q*(2*norm/15) - norm
        int qs[8] = {a4.x, a4.y, a4.z, a4.w, c4.x, c4.y, c4.z, c4.w};
        bf16x8 v0, v1;
#pragma unroll
        for (int u = 0; u < 8; ++u) {
            float lo = fmaf((float)(qs[u] & 15), s, -nm);
            float hi = fmaf((float)((qs[u] >> 4) & 15), s, -nm);
            if (u < 4) { v0[2 * u] = (__bf16)lo; v0[2 * u + 1] = (__bf16)hi; }
            else       { v1[2 * (u - 4)] = (__bf16)lo; v1[2 * (u - 4) + 1] = (__bf16)hi; }
        }
        bf16x8* wp = (bf16x8*)(W + (size_t)t * 16);
        wp[0] = v0; wp[1] = v1;
    } else {
        // ---- x convert: grid-stride over M*K/8 vectors of 8 ----
        if (s_modes[0] == 1) return;   // x already bf16: GEMM reads it directly
        const int bx = blockIdx.x - 4096;                 // 0..2047
        const int total8 = M_TOK * K_IN / 8;
        const int stride = 2048 * 256;
        for (int i = bx * 256 + tid; i < total8; i += stride) {
            const float4* fp = (const float4*)xv + (size_t)i * 2;
            float4 f0 = fp[0], f1 = fp[1];
            bf16x8 u;
            u[0] = (__bf16)f0.x; u[1] = (__bf16)f0.y; u[2] = (__bf16)f0.z; u[3] = (__bf16)f0.w;
            u[4] = (__bf16)f1.x; u[5] = (__bf16)f1.y; u[6] = (__bf16)f1.z; u[7] = (__bf16)f1.w;
            *(bf16x8*)(X + (size_t)i * 8) = u;
        }
    }
}

// ---------------------------------------------------------------------------
// GEMM: m97-structure, 128x128 tile, BK=32, 4 waves (2x2), 4x4 MFMA 16x16x32
// bf16 per wave. Staging via global_load_lds dwordx4 (16B/lane), linear LDS.
// New this round: XCD-bijective blockIdx swizzle (T1; nwg=2048, 2048%8==0 so
// the simple form is bijective) — each XCD gets a contiguous 8-m-panel chunk
// so concurrent same-XCD blocks share the x panel in their private L2.
// Detection inlined per block (replaces the modes workspace dependency).
// ---------------------------------------------------------------------------
__global__ __launch_bounds__(256, 3) void gemm_glds(
        const void* __restrict__ xv, const __bf16* __restrict__ Xws,
        const __bf16* __restrict__ W, const void* __restrict__ nrmv,
        const void* __restrict__ biasv, float* __restrict__ out) {
    __shared__ __align__(16) __bf16 As[128 * 32];
    __shared__ __align__(16) __bf16 Bs[128 * 32];
    __shared__ int s_modes[3];

    detect_block(xv, nrmv, biasv, s_modes);
    const int xmode = s_modes[0];
    const int bmode = s_modes[2];
    const __bf16* A = xmode ? (const __bf16*)xv : Xws;

    // XCD-aware bijective swizzle: XCD k owns bid in [k*256,(k+1)*256)
    const int bid = ((blockIdx.x & 7) << 8) + (blockIdx.x >> 3);
    const int n0 = (bid & 31) * 128;   // n fastest within chunk: share x panel
    const int m0 = (bid >> 5) * 128;

    const int tid = threadIdx.x;
    const int w  = tid >> 6;   // wave id 0..3
    const int l  = tid & 63;   // lane
    const int r  = l & 15;
    const int q  = l >> 4;
    const int wm = (w >> 1) * 64;
    const int wn = (w & 1) * 64;

    // glds addressing: chunk c covers tile rows [c*16, c*16+16), 1 KiB LDS.
    // lane l -> row c*16 + (l>>2), col (l&3)*8 elements (16B).
    const int c0 = w * 2;                       // this wave's chunks: c0, c0+1
    const int lr = l >> 2;
    const int lc = (l & 3) * 8;
    const __bf16* ga0 = A + (size_t)(m0 + c0 * 16 + lr) * K_IN + lc;
    const __bf16* gb0 = W + (size_t)(n0 + c0 * 16 + lr) * K_IN + lc;
    __bf16* la0 = As + c0 * 512;                // c*1024 bytes
    __bf16* lb0 = Bs + c0 * 512;

    // bias folded into accumulator init: C/D col = lane&15 = r
    f32x4 acc[4][4];
#pragma unroll
    for (int j = 0; j < 4; ++j) {
        const int bidx = n0 + wn + j * 16 + r;
        float bv = (bmode == 0) ? ((const float*)biasv)[bidx]
                                : bfbits(((const unsigned short*)biasv)[bidx]);
#pragma unroll
        for (int i = 0; i < 4; ++i) {
            acc[i][j][0] = bv; acc[i][j][1] = bv; acc[i][j][2] = bv; acc[i][j][3] = bv;
        }
    }

    for (int k0 = 0; k0 < K_IN; k0 += 32) {
        __syncthreads();   // previous iteration's LDS reads complete
        GLDS16(ga0 + k0,                      la0);
        GLDS16(ga0 + k0 + (size_t)16 * K_IN,  la0 + 512);
        GLDS16(gb0 + k0,                      lb0);
        GLDS16(gb0 + k0 + (size_t)16 * K_IN,  lb0 + 512);
        __syncthreads();   // vmcnt(0) drain before s_barrier: tile ready

        bf16x8 af[4], bf[4];
#pragma unroll
        for (int i = 0; i < 4; ++i)
            af[i] = *(const bf16x8*)(As + (wm + i * 16 + r) * 32 + q * 8);
#pragma unroll
        for (int j = 0; j < 4; ++j)
            bf[j] = *(const bf16x8*)(Bs + (wn + j * 16 + r) * 32 + q * 8);

#pragma unroll
        for (int i = 0; i < 4; ++i)
#pragma unroll
            for (int j = 0; j < 4; ++j)
                acc[i][j] = __builtin_amdgcn_mfma_f32_16x16x32_bf16(
                    af[i], bf[j], acc[i][j], 0, 0, 0);
    }

    // epilogue: C/D map col=lane&15, row=(lane>>4)*4+reg  (m89-verified)
#pragma unroll
    for (int i = 0; i < 4; ++i) {
        const int row = m0 + wm + i * 16 + q * 4;
#pragma unroll
        for (int j = 0; j < 4; ++j) {
            const int col = n0 + wn + j * 16 + r;
            float* p = out + (size_t)row * N_OUT + col;
            p[0 * N_OUT] = acc[i][j][0];
            p[1 * N_OUT] = acc[i][j][1];
            p[2 * N_OUT] = acc[i][j][2];
            p[3 * N_OUT] = acc[i][j][3];
        }
    }
}

// ---------------------------------------------------------------------------
// Fallback: the round-0 verified fused kernel (used only if ws too small).
// ---------------------------------------------------------------------------
__global__ __launch_bounds__(256, 2) void gemm_fused(
        const void* __restrict__ xv,
        const int* __restrict__ q4, const void* __restrict__ nrmv,
        const void* __restrict__ biasv, float* __restrict__ out) {
    __shared__ __align__(16) __bf16 As[128 * 32];
    __shared__ __align__(16) __bf16 Bs[128 * 32];
    __shared__ int s_modes[3];

    detect_block(xv, nrmv, biasv, s_modes);
    const int tid = threadIdx.x;
    const int xmode = s_modes[0];
    const int nmode = s_modes[1];
    const int bmode = s_modes[2];

    const int bid = blockIdx.x;
    const int n0 = (bid & 31) * 128;
    const int m0 = (bid >> 5) * 128;

    const int w  = tid >> 6;
    const int l  = tid & 63;
    const int r  = l & 15;
    const int q  = l >> 4;
    const int wm = (w >> 1) * 64;
    const int wn = (w & 1) * 64;

    const int arow = tid >> 1;
    const int acol = (tid & 1) * 16;
    const size_t aoff = (size_t)(m0 + arow) * K_IN + acol;

    const int brow = tid >> 1;
    const int bgc  = tid & 1;

    f32x4 acc[4][4];
#pragma unroll
    for (int j = 0; j < 4; ++j) {
        const int bidx = n0 + wn + j * 16 + r;
        float bv = (bmode == 0) ? ((const float*)biasv)[bidx]
                                : bfbits(((const unsigned short*)biasv)[bidx]);
#pragma unroll
        for (int i = 0; i < 4; ++i) {
            acc[i][j][0] = bv; acc[i][j][1] = bv; acc[i][j][2] = bv; acc[i][j][3] = bv;
        }
    }

    for (int k0 = 0; k0 < K_IN; k0 += 32) {
        __syncthreads();
        {
            const int g = (n0 + brow) * (K_IN / GRP) + (k0 >> 4) + bgc;
            const int4* qp = (const int4*)q4 + (size_t)g * 2;
            int4 a4 = qp[0], c4 = qp[1];
            float nm;
            if (nmode == 0)      nm = __half2float(((const __half*)nrmv)[g]);
            else if (nmode == 1) nm = bfbits(((const unsigned short*)nrmv)[g]);
            else                 nm = ((const float*)nrmv)[g];
            float s = nm * (2.0f / 15.0f);
            int qs[8] = {a4.x, a4.y, a4.z, a4.w, c4.x, c4.y, c4.z, c4.w};
            bf16x8 v0, v1;
#pragma unroll
            for (int u = 0; u < 8; ++u) {
                float lo = fmaf((float)(qs[u] & 15), s, -nm);
                float hi = fmaf((float)((qs[u] >> 4) & 15), s, -nm);
                if (u < 4) { v0[2 * u] = (__bf16)lo; v0[2 * u + 1] = (__bf16)hi; }
                else       { v1[2 * (u - 4)] = (__bf16)lo; v1[2 * (u - 4) + 1] = (__bf16)hi; }
            }
            bf16x8* bp = (bf16x8*)(Bs + brow * 32 + bgc * 16);
            bp[0] = v0; bp[1] = v1;
        }

        if (xmode == 0) {
            const float4* ap = (const float4*)((const float*)xv + aoff + k0);
            float4 f0 = ap[0], f1 = ap[1], f2 = ap[2], f3 = ap[3];
            bf16x8 u0, u1;
            u0[0] = (__bf16)f0.x; u0[1] = (__bf16)f0.y; u0[2] = (__bf16)f0.z; u0[3] = (__bf16)f0.w;
            u0[4] = (__bf16)f1.x; u0[5] = (__bf16)f1.y; u0[6] = (__bf16)f1.z; u0[7] = (__bf16)f1.w;
            u1[0] = (__bf16)f2.x; u1[1] = (__bf16)f2.y; u1[2] = (__bf16)f2.z; u1[3] = (__bf16)f2.w;
            u1[4] = (__bf16)f3.x; u1[5] = (__bf16)f3.y; u1[6] = (__bf16)f3.z; u1[7] = (__bf16)f3.w;
            bf16x8* asp = (bf16x8*)(As + arow * 32 + acol);
            asp[0] = u0; asp[1] = u1;
        } else {
            const ushort8* ap = (const ushort8*)((const unsigned short*)xv + aoff + k0);
            ushort8 u0 = ap[0], u1 = ap[1];
            bf16x8* asp = (bf16x8*)(As + arow * 32 + acol);
            asp[0] = __builtin_bit_cast(bf16x8, u0);
            asp[1] = __builtin_bit_cast(bf16x8, u1);
        }

        __syncthreads();

        bf16x8 af[4], bf[4];
#pragma unroll
        for (int i = 0; i < 4; ++i)
            af[i] = *(const bf16x8*)(As + (wm + i * 16 + r) * 32 + q * 8);
#pragma unroll
        for (int j = 0; j < 4; ++j)
            bf[j] = *(const bf16x8*)(Bs + (wn + j * 16 + r) * 32 + q * 8);

#pragma unroll
        for (int i = 0; i < 4; ++i)
#pragma unroll
            for (int j = 0; j < 4; ++j)
                acc[i][j] = __builtin_amdgcn_mfma_f32_16x16x32_bf16(
                    af[i], bf[j], acc[i][j], 0, 0, 0);
    }

#pragma unroll
    for (int i = 0; i < 4; ++i) {
        const int row = m0 + wm + i * 16 + q * 4;
#pragma unroll
        for (int j = 0; j < 4; ++j) {
            const int col = n0 + wn + j * 16 + r;
            float* p = out + (size_t)row * N_OUT + col;
            p[0 * N_OUT] = acc[i][j][0];
            p[1 * N_OUT] = acc[i][j][1];
            p[2 * N_OUT] = acc[i][j][2];
            p[3 * N_OUT] = acc[i][j][3];
        }
    }
}

extern "C" void kernel_launch(void* const* d_in, const int* in_sizes, int n_in,
                              void* d_out, int out_size, void* d_ws, size_t ws_size,
                              hipStream_t stream) {
    const void* x    = d_in[0];
    const int*  q4   = (const int*)d_in[1];
    const void* nrm  = d_in[2];
    const void* bias = d_in[3];
    float*      out  = (float*)d_out;

    // workspace layout: [W bf16: N*K*2][X bf16: M*K*2]
    const size_t X_OFF = (size_t)N_OUT * K_IN * 2;
    const size_t NEED  = X_OFF + (size_t)M_TOK * K_IN * 2;   // ~100.7 MB

    if (ws_size >= NEED) {
        __bf16* W = (__bf16*)d_ws;
        __bf16* X = (__bf16*)((char*)d_ws + X_OFF);

        prep_all<<<4096 + 2048, 256, 0, stream>>>(x, q4, nrm, bias, W, X);
        gemm_glds<<<(M_TOK / 128) * (N_OUT / 128), 256, 0, stream>>>(
            x, X, W, nrm, bias, out);
    } else {
        gemm_fused<<<(M_TOK / 128) * (N_OUT / 128), 256, 0, stream>>>(
            x, q4, nrm, bias, out);
    }
}

// Round 3
// 570.573 us; speedup vs baseline: 1.0203x; 1.0203x over previous
//
#include <hip/hip_runtime.h>
#include <hip/hip_fp16.h>

// Problem constants (from reference): OUT=4096, IN=4096, G=16, TOK=8192
#define M_TOK 8192
#define N_OUT 4096
#define K_IN  4096
#define GRP   16

typedef __bf16 bf16x8 __attribute__((ext_vector_type(8)));
typedef float  f32x4  __attribute__((ext_vector_type(4)));
typedef unsigned short ushort8 __attribute__((ext_vector_type(8)));

__device__ __forceinline__ float bfbits(unsigned short h) {
    unsigned int u = ((unsigned int)h) << 16;
    return __builtin_bit_cast(float, u);
}

// async global->LDS, 16B per lane. LDS dest = wave-uniform base + lane*16 (linear).
#define GLDS16(gp, sp) __builtin_amdgcn_global_load_lds(                      \
        (const __attribute__((address_space(1))) void*)(gp),                  \
        (__attribute__((address_space(3))) void*)(sp), 16, 0, 0)

// ---------------------------------------------------------------------------
// Wave-parallel dtype detection (per block).
//   s_modes[0]: x storage    1=bf16, 0=f32   (even halfwords 0..126)
//   s_modes[1]: norm storage 0=fp16, 1=bf16, 2=f32  (halfwords 0..31)
//   s_modes[2]: bias storage 1=bf16, 0=f32   (even halfwords 0..126)
// ---------------------------------------------------------------------------
__device__ __forceinline__ void detect_block(const void* __restrict__ xv,
                                             const void* __restrict__ nrmv,
                                             const void* __restrict__ biasv,
                                             int* s_modes) {
    const int tid = threadIdx.x;
    if (tid < 64) {
        const unsigned short* px = (const unsigned short*)xv;
        unsigned short hx = px[tid * 2];
        int ex = (hx >> 7) & 0xFF;
        bool xok = ((ex >= 64 && ex <= 134) || (hx & 0x7FFF) == 0);
        unsigned long long xb = __ballot(xok);

        const unsigned short* pn = (const unsigned short*)nrmv;
        unsigned short hn = pn[tid & 31];   // lanes 32..63 duplicate 0..31
        float v16 = __half2float(__builtin_bit_cast(__half, hn));
        float vbf = bfbits(hn);
        unsigned long long b16 = __ballot(v16 > 0.0085f && v16 < 1.02f);  // NaN->false
        unsigned long long bbf = __ballot(vbf > 0.0085f && vbf < 1.02f);

        const unsigned short* pb = (const unsigned short*)biasv;
        unsigned short hb = pb[tid * 2];
        int eb = (hb >> 7) & 0xFF;
        bool bok = ((eb >= 64 && eb <= 134) || (hb & 0x7FFF) == 0);
        unsigned long long bb = __ballot(bok);

        if (tid == 0) {
            s_modes[0] = (xb == ~0ULL) ? 1 : 0;
            s_modes[1] = (b16 == ~0ULL) ? 0 : ((bbf == ~0ULL) ? 1 : 2);
            s_modes[2] = (bb == ~0ULL) ? 1 : 0;
        }
    }
    __syncthreads();
}

// ---------------------------------------------------------------------------
// Fused prep kernel: blocks [0,4096) dequant W -> bf16 ws; blocks [4096,6144)
// convert x f32->bf16 ws (early-exit if x already bf16).
// ---------------------------------------------------------------------------
__global__ __launch_bounds__(256) void prep_all(const void* __restrict__ xv,
                                                const int* __restrict__ q4,
                                                const void* __restrict__ nrmv,
                                                const void* __restrict__ biasv,
                                                __bf16* __restrict__ W,
                                                __bf16* __restrict__ X) {
    __shared__ int s_modes[3];
    detect_block(xv, nrmv, biasv, s_modes);
    const int tid = threadIdx.x;

    if (blockIdx.x < 4096) {
        const int nmode = s_modes[1];
        const int t = blockIdx.x * 256 + tid;              // 0 .. N*K/G-1
        const int4* qp = (const int4*)q4 + (size_t)t * 2;  // 8 int32 = 16 nibble pairs
        int4 a4 = qp[0], c4 = qp[1];
        float nm;
        if (nmode == 0)      nm = __half2float(((const __half*)nrmv)[t]);
        else if (nmode == 1) nm = bfbits(((const unsigned short*)nrmv)[t]);
        else                 nm = ((const float*)nrmv)[t];
        float s = nm * (2.0f / 15.0f);   // w = q*(2*norm/15) - norm
        int qs[8] = {a4.x, a4.y, a4.z, a4.w, c4.x, c4.y, c4.z, c4.w};
        bf16x8 v0, v1;
#pragma unroll
        for (int u = 0; u < 8; ++u) {
            float lo = fmaf((float)(qs[u] & 15), s, -nm);
            float hi = fmaf((float)((qs[u] >> 4) & 15), s, -nm);
            if (u < 4) { v0[2 * u] = (__bf16)lo; v0[2 * u + 1] = (__bf16)hi; }
            else       { v1[2 * (u - 4)] = (__bf16)lo; v1[2 * (u - 4) + 1] = (__bf16)hi; }
        }
        bf16x8* wp = (bf16x8*)(W + (size_t)t * 16);
        wp[0] = v0; wp[1] = v1;
    } else {
        if (s_modes[0] == 1) return;   // x already bf16
        const int bx = blockIdx.x - 4096;                 // 0..2047
        const int total8 = M_TOK * K_IN / 8;
        const int stride = 2048 * 256;
        for (int i = bx * 256 + tid; i < total8; i += stride) {
            const float4* fp = (const float4*)xv + (size_t)i * 2;
            float4 f0 = fp[0], f1 = fp[1];
            bf16x8 u;
            u[0] = (__bf16)f0.x; u[1] = (__bf16)f0.y; u[2] = (__bf16)f0.z; u[3] = (__bf16)f0.w;
            u[4] = (__bf16)f1.x; u[5] = (__bf16)f1.y; u[6] = (__bf16)f1.z; u[7] = (__bf16)f1.w;
            *(bf16x8*)(X + (size_t)i * 8) = u;
        }
    }
}

// ---------------------------------------------------------------------------
// GEMM: 256x256 tile, BK=32, 512 threads = 8 waves (2M x 4N), per-wave output
// 128x64 (acc[8][4] of 16x16 frags). Deep pipeline:
//   - triple-buffered LDS (3 x 32KB): compute tile t from buf[t%3] while
//     global_load_lds stages tile t+2 into buf[(t+2)%3] (dead buffer => the
//     async writes can never race with reads; proof: readers of that buffer
//     finished before the barrier two iterations ago).
//   - ONE raw s_barrier + s_waitcnt vmcnt(4) per K-tile (4 glds/wave/tile):
//     tile t+1's 4 loads proven landed, tile t+2's 4 stay in flight across
//     the barrier (T4, counted vmcnt — never vmcnt(0) in the loop).
//   - bank-conflict swizzle at zero VALU cost: LDS slot (row, 16B-block b)
//     holds global k-block b^(row&3). Write side: LDS stays linear (glds
//     requirement), the per-lane GLOBAL source address is pre-swizzled
//     (row&3 == (l>>2)&3, lane-constant). Read side: block q^(r&3),
//     lane-constant => folds into base. 8-way -> 4-way frag-read conflicts.
//   - s_setprio(1/0) around the MFMA cluster (T5).
// ---------------------------------------------------------------------------
__global__ __launch_bounds__(512, 2) void gemm256(
        const void* __restrict__ xv, const __bf16* __restrict__ Xws,
        const __bf16* __restrict__ W, const void* __restrict__ nrmv,
        const void* __restrict__ biasv, float* __restrict__ out) {
    __shared__ __align__(16) __bf16 As3[3 * 8192];   // 3 x [256][32]
    __shared__ __align__(16) __bf16 Bs3[3 * 8192];
    __shared__ int s_modes[3];

    detect_block(xv, nrmv, biasv, s_modes);
    const int xmode = s_modes[0];
    const int bmode = s_modes[2];
    const __bf16* A = xmode ? (const __bf16*)xv : Xws;

    const int bid = blockIdx.x;                 // no XCD swizzle (r2: regressed, L3-fit)
    const int n0 = (bid & 15) * 256;
    const int m0 = (bid >> 4) * 256;

    const int tid = threadIdx.x;
    const int w  = tid >> 6;        // wave 0..7
    const int l  = tid & 63;
    const int r  = l & 15;
    const int q  = l >> 4;          // 0..3
    const int wm = (w >> 2) * 128;  // waves 0-3 -> rows 0-127, 4-7 -> 128-255
    const int wn = (w & 3) * 64;
    const int xq8 = (q ^ (r & 3)) * 8;          // swizzled read block (elements)

    // staging: per 128-row round, lane covers row rr = w*16 + (l>>2),
    // LDS block l&3; global k-block (l&3)^(rr&3)  (rr&3 == (l>>2)&3).
    const int rr    = w * 16 + (l >> 2);
    const int cperm = ((l & 3) ^ ((l >> 2) & 3)) * 8;
    const __bf16* gA = A + (size_t)(m0 + rr) * K_IN + cperm;
    const __bf16* gB = W + (size_t)(n0 + rr) * K_IN + cperm;
    __bf16* laB = As3 + w * 512;    // + b*8192 + round*4096 (elements)
    __bf16* lbB = Bs3 + w * 512;

    auto stage = [&](int t, int b) {
        const __bf16* at = gA + t * 32;
        const __bf16* bt = gB + t * 32;
        __bf16* la = laB + b * 8192;
        __bf16* lb = lbB + b * 8192;
        GLDS16(at,                       la);            // A rows   0-127
        GLDS16(at + (size_t)128 * K_IN,  la + 4096);     // A rows 128-255
        GLDS16(bt,                       lb);            // B rows   0-127
        GLDS16(bt + (size_t)128 * K_IN,  lb + 4096);     // B rows 128-255
    };

    // bias folded into accumulator init: C/D col = lane&15 = r
    f32x4 acc[8][4];
#pragma unroll
    for (int j = 0; j < 4; ++j) {
        const int bidx = n0 + wn + j * 16 + r;
        float bv = (bmode == 0) ? ((const float*)biasv)[bidx]
                                : bfbits(((const unsigned short*)biasv)[bidx]);
#pragma unroll
        for (int i = 0; i < 8; ++i) {
            acc[i][j][0] = bv; acc[i][j][1] = bv; acc[i][j][2] = bv; acc[i][j][3] = bv;
        }
    }

    auto compute = [&](int b) {
        const __bf16* Ab = As3 + b * 8192;
        const __bf16* Bb = Bs3 + b * 8192;
        bf16x8 af[8], bfr[4];
#pragma unroll
        for (int i = 0; i < 8; ++i)
            af[i] = *(const bf16x8*)(Ab + (wm + i * 16 + r) * 32 + xq8);
#pragma unroll
        for (int j = 0; j < 4; ++j)
            bfr[j] = *(const bf16x8*)(Bb + (wn + j * 16 + r) * 32 + xq8);
        __builtin_amdgcn_s_setprio(1);
#pragma unroll
        for (int i = 0; i < 8; ++i)
#pragma unroll
            for (int j = 0; j < 4; ++j)
                acc[i][j] = __builtin_amdgcn_mfma_f32_16x16x32_bf16(
                    af[i], bfr[j], acc[i][j], 0, 0, 0);
        __builtin_amdgcn_s_setprio(0);
    };

    const int NT = K_IN / 32;    // 128 K-tiles

    // prologue: stage tiles 0,1; wait tile 0 (4 of 8 loads still in flight)
    stage(0, 0);
    stage(1, 1);
    asm volatile("s_waitcnt vmcnt(4)" ::: "memory");
    __builtin_amdgcn_s_barrier();

    int bc = 0, bs = 2;
    for (int t = 0; t < NT - 2; ++t) {
        stage(t + 2, bs);            // into dead buffer (t+2)%3
        compute(bc);                 // tile t from buf t%3
        __builtin_amdgcn_sched_barrier(0);               // pin reads/MFMAs above
        asm volatile("s_waitcnt vmcnt(4)" ::: "memory"); // tile t+1 landed
        __builtin_amdgcn_s_barrier();
        bc = (bc == 2) ? 0 : bc + 1;
        bs = (bs == 2) ? 0 : bs + 1;
    }
    // tail: tile NT-2 (landed), then drain tile NT-1's loads
    compute(bc);
    __builtin_amdgcn_sched_barrier(0);
    asm volatile("s_waitcnt vmcnt(0)" ::: "memory");
    __builtin_amdgcn_s_barrier();
    bc = (bc == 2) ? 0 : bc + 1;
    compute(bc);

    // epilogue: C/D map col=lane&15, row=(lane>>4)*4+reg  (m89-verified)
#pragma unroll
    for (int i = 0; i < 8; ++i) {
        const int row = m0 + wm + i * 16 + q * 4;
#pragma unroll
        for (int j = 0; j < 4; ++j) {
            const int col = n0 + wn + j * 16 + r;
            float* p = out + (size_t)row * N_OUT + col;
            p[0 * N_OUT] = acc[i][j][0];
            p[1 * N_OUT] = acc[i][j][1];
            p[2 * N_OUT] = acc[i][j][2];
            p[3 * N_OUT] = acc[i][j][3];
        }
    }
}

// ---------------------------------------------------------------------------
// Fallback: the round-0 verified fused kernel (used only if ws too small).
// ---------------------------------------------------------------------------
__global__ __launch_bounds__(256, 2) void gemm_fused(
        const void* __restrict__ xv,
        const int* __restrict__ q4, const void* __restrict__ nrmv,
        const void* __restrict__ biasv, float* __restrict__ out) {
    __shared__ __align__(16) __bf16 As[128 * 32];
    __shared__ __align__(16) __bf16 Bs[128 * 32];
    __shared__ int s_modes[3];

    detect_block(xv, nrmv, biasv, s_modes);
    const int tid = threadIdx.x;
    const int xmode = s_modes[0];
    const int nmode = s_modes[1];
    const int bmode = s_modes[2];

    const int bid = blockIdx.x;
    const int n0 = (bid & 31) * 128;
    const int m0 = (bid >> 5) * 128;

    const int w  = tid >> 6;
    const int l  = tid & 63;
    const int r  = l & 15;
    const int q  = l >> 4;
    const int wm = (w >> 1) * 64;
    const int wn = (w & 1) * 64;

    const int arow = tid >> 1;
    const int acol = (tid & 1) * 16;
    const size_t aoff = (size_t)(m0 + arow) * K_IN + acol;

    const int brow = tid >> 1;
    const int bgc  = tid & 1;

    f32x4 acc[4][4];
#pragma unroll
    for (int j = 0; j < 4; ++j) {
        const int bidx = n0 + wn + j * 16 + r;
        float bv = (bmode == 0) ? ((const float*)biasv)[bidx]
                                : bfbits(((const unsigned short*)biasv)[bidx]);
#pragma unroll
        for (int i = 0; i < 4; ++i) {
            acc[i][j][0] = bv; acc[i][j][1] = bv; acc[i][j][2] = bv; acc[i][j][3] = bv;
        }
    }

    for (int k0 = 0; k0 < K_IN; k0 += 32) {
        __syncthreads();
        {
            const int g = (n0 + brow) * (K_IN / GRP) + (k0 >> 4) + bgc;
            const int4* qp = (const int4*)q4 + (size_t)g * 2;
            int4 a4 = qp[0], c4 = qp[1];
            float nm;
            if (nmode == 0)      nm = __half2float(((const __half*)nrmv)[g]);
            else if (nmode == 1) nm = bfbits(((const unsigned short*)nrmv)[g]);
            else                 nm = ((const float*)nrmv)[g];
            float s = nm * (2.0f / 15.0f);
            int qs[8] = {a4.x, a4.y, a4.z, a4.w, c4.x, c4.y, c4.z, c4.w};
            bf16x8 v0, v1;
#pragma unroll
            for (int u = 0; u < 8; ++u) {
                float lo = fmaf((float)(qs[u] & 15), s, -nm);
                float hi = fmaf((float)((qs[u] >> 4) & 15), s, -nm);
                if (u < 4) { v0[2 * u] = (__bf16)lo; v0[2 * u + 1] = (__bf16)hi; }
                else       { v1[2 * (u - 4)] = (__bf16)lo; v1[2 * (u - 4) + 1] = (__bf16)hi; }
            }
            bf16x8* bp = (bf16x8*)(Bs + brow * 32 + bgc * 16);
            bp[0] = v0; bp[1] = v1;
        }

        if (xmode == 0) {
            const float4* ap = (const float4*)((const float*)xv + aoff + k0);
            float4 f0 = ap[0], f1 = ap[1], f2 = ap[2], f3 = ap[3];
            bf16x8 u0, u1;
            u0[0] = (__bf16)f0.x; u0[1] = (__bf16)f0.y; u0[2] = (__bf16)f0.z; u0[3] = (__bf16)f0.w;
            u0[4] = (__bf16)f1.x; u0[5] = (__bf16)f1.y; u0[6] = (__bf16)f1.z; u0[7] = (__bf16)f1.w;
            u1[0] = (__bf16)f2.x; u1[1] = (__bf16)f2.y; u1[2] = (__bf16)f2.z; u1[3] = (__bf16)f2.w;
            u1[4] = (__bf16)f3.x; u1[5] = (__bf16)f3.y; u1[6] = (__bf16)f3.z; u1[7] = (__bf16)f3.w;
            bf16x8* asp = (bf16x8*)(As + arow * 32 + acol);
            asp[0] = u0; asp[1] = u1;
        } else {
            const ushort8* ap = (const ushort8*)((const unsigned short*)xv + aoff + k0);
            ushort8 u0 = ap[0], u1 = ap[1];
            bf16x8* asp = (bf16x8*)(As + arow * 32 + acol);
            asp[0] = __builtin_bit_cast(bf16x8, u0);
            asp[1] = __builtin_bit_cast(bf16x8, u1);
        }

        __syncthreads();

        bf16x8 af[4], bf[4];
#pragma unroll
        for (int i = 0; i < 4; ++i)
            af[i] = *(const bf16x8*)(As + (wm + i * 16 + r) * 32 + q * 8);
#pragma unroll
        for (int j = 0; j < 4; ++j)
            bf[j] = *(const bf16x8*)(Bs + (wn + j * 16 + r) * 32 + q * 8);

#pragma unroll
        for (int i = 0; i < 4; ++i)
#pragma unroll
            for (int j = 0; j < 4; ++j)
                acc[i][j] = __builtin_amdgcn_mfma_f32_16x16x32_bf16(
                    af[i], bf[j], acc[i][j], 0, 0, 0);
    }

#pragma unroll
    for (int i = 0; i < 4; ++i) {
        const int row = m0 + wm + i * 16 + q * 4;
#pragma unroll
        for (int j = 0; j < 4; ++j) {
            const int col = n0 + wn + j * 16 + r;
            float* p = out + (size_t)row * N_OUT + col;
            p[0 * N_OUT] = acc[i][j][0];
            p[1 * N_OUT] = acc[i][j][1];
            p[2 * N_OUT] = acc[i][j][2];
            p[3 * N_OUT] = acc[i][j][3];
        }
    }
}

extern "C" void kernel_launch(void* const* d_in, const int* in_sizes, int n_in,
                              void* d_out, int out_size, void* d_ws, size_t ws_size,
                              hipStream_t stream) {
    const void* x    = d_in[0];
    const int*  q4   = (const int*)d_in[1];
    const void* nrm  = d_in[2];
    const void* bias = d_in[3];
    float*      out  = (float*)d_out;

    // workspace layout: [W bf16: N*K*2][X bf16: M*K*2]
    const size_t X_OFF = (size_t)N_OUT * K_IN * 2;
    const size_t NEED  = X_OFF + (size_t)M_TOK * K_IN * 2;   // ~100.7 MB

    if (ws_size >= NEED) {
        __bf16* W = (__bf16*)d_ws;
        __bf16* X = (__bf16*)((char*)d_ws + X_OFF);

        prep_all<<<4096 + 2048, 256, 0, stream>>>(x, q4, nrm, bias, W, X);
        gemm256<<<(M_TOK / 256) * (N_OUT / 256), 512, 0, stream>>>(
            x, X, W, nrm, bias, out);
    } else {
        gemm_fused<<<(M_TOK / 128) * (N_OUT / 128), 256, 0, stream>>>(
            x, q4, nrm, bias, out);
    }
}